// Round 7
// baseline (337.790 us; speedup 1.0000x reference)
//
#include <hip/hip_runtime.h>

#define GM_EPS 1e-8f
#define TILE 128           // Gaussians per tile; 2,000,000 % 128 == 0
#define NT4  960           // float4-chunks per input tile  (TILE*30 floats / 4)
#define OUT4 384           // float4-chunks per output tile (TILE*12 floats / 4)
#define GRID 1792          // 7 blocks/CU * 256 CU (LDS-capped occupancy)

typedef float f4 __attribute__((ext_vector_type(4)));

// Map flat float4-index k in the tile's packed input layout
// [rot1(288)][rot2(288)][loc1(96)][loc2(96)][s1(96)][s2(96)] to a global load.
__device__ __forceinline__ f4 load_in(
    const f4* __restrict__ r1, const f4* __restrict__ r2,
    const f4* __restrict__ p1, const f4* __restrict__ p2,
    const f4* __restrict__ q1, const f4* __restrict__ q2,
    long t, int k)
{
    const f4* p;
    long off;
    if (k < 288)      { p = r1; off = t * 288 + k; }
    else if (k < 576) { p = r2; off = t * 288 + (k - 288); }
    else if (k < 672) { p = p1; off = t * 96  + (k - 576); }
    else if (k < 768) { p = p2; off = t * 96  + (k - 672); }
    else if (k < 864) { p = q1; off = t * 96  + (k - 768); }
    else              { p = q2; off = t * 96  + (k - 864); }
    return p[off];
}

__global__ __launch_bounds__(TILE) void gaussian_merge_kernel(
    const float* __restrict__ loc1,
    const float* __restrict__ scale1,
    const float* __restrict__ rot1,
    const float* __restrict__ loc2,
    const float* __restrict__ scale2,
    const float* __restrict__ rot2,
    float* __restrict__ out_loc,   // [n,3]
    float* __restrict__ out_cov,   // [n,3,3]
    int nTiles)
{
    // sIn: packed input tile (15360 B). sOut: packed output tile (6144 B),
    // laid out exactly like global: [loc_new 384 f][cov_new 1152 f].
    __shared__ alignas(16) f4    sIn[NT4];
    __shared__ alignas(16) float sOut[TILE * 12];

    const int tid = threadIdx.x;

    const f4* r1 = (const f4*)rot1;
    const f4* r2 = (const f4*)rot2;
    const f4* p1 = (const f4*)loc1;
    const f4* p2 = (const f4*)loc2;
    const f4* q1 = (const f4*)scale1;
    const f4* q2 = (const f4*)scale2;

    long t = blockIdx.x;
    f4 pre[8];
    if (t < nTiles) {
#pragma unroll
        for (int u = 0; u < 8; ++u) {
            int k = tid + TILE * u;
            if (k < NT4) pre[u] = load_in(r1, r2, p1, p2, q1, q2, t, k);
        }
    }

    for (; t < nTiles; t += gridDim.x) {
        // ---- drain prefetched tile t into LDS ----
#pragma unroll
        for (int u = 0; u < 8; ++u) {
            int k = tid + TILE * u;
            if (k < NT4) sIn[k] = pre[u];
        }
        __syncthreads();   // barrier 1: sIn ready; prior store-phase sOut reads done

        // ---- issue tile t+stride loads EARLY: in flight under compute+store ----
        const long tn = t + gridDim.x;
        if (tn < nTiles) {
#pragma unroll
            for (int u = 0; u < 8; ++u) {
                int k = tid + TILE * u;
                if (k < NT4) pre[u] = load_in(r1, r2, p1, p2, q1, q2, tn, k);
            }
        }

        // ---- per-thread compute from LDS (registers only) ----
        {
            const float* sInf = (const float*)sIn;
            float R1[9], R2[9], l1[3], l2[3], s1[3], s2[3];
#pragma unroll
            for (int k = 0; k < 9; ++k) {
                R1[k] = sInf[tid * 9 + k];
                R2[k] = sInf[1152 + tid * 9 + k];
            }
#pragma unroll
            for (int k = 0; k < 3; ++k) {
                l1[k] = sInf[2304 + tid * 3 + k];
                l2[k] = sInf[2688 + tid * 3 + k];
                s1[k] = sInf[3072 + tid * 3 + k];
                s2[k] = sInf[3456 + tid * 3 + k];
            }

            // c1 = R1 diag(s1) R1^T ; S = c1 + c2 + eps*I
            float c1[3][3], S[3][3];
#pragma unroll
            for (int a = 0; a < 3; ++a) {
#pragma unroll
                for (int b = 0; b < 3; ++b) {
                    float v1 = 0.f, v2 = 0.f;
#pragma unroll
                    for (int k = 0; k < 3; ++k) {
                        v1 = fmaf(R1[a * 3 + k] * s1[k], R1[b * 3 + k], v1);
                        v2 = fmaf(R2[a * 3 + k] * s2[k], R2[b * 3 + k], v2);
                    }
                    c1[a][b] = v1;
                    S[a][b]  = v1 + v2 + (a == b ? GM_EPS : 0.f);
                }
            }

            // Sinv = inv(S), adjugate of symmetric 3x3
            const float m00 = S[0][0], m01 = S[0][1], m02 = S[0][2];
            const float m11 = S[1][1], m12 = S[1][2], m22 = S[2][2];
            const float A0 = m11 * m22 - m12 * m12;
            const float A1 = m02 * m12 - m01 * m22;
            const float A2 = m01 * m12 - m02 * m11;
            const float det    = m00 * A0 + m01 * A1 + m02 * A2;
            const float invdet = 1.0f / det;

            float Sinv[3][3];
            Sinv[0][0] = A0 * invdet;
            Sinv[0][1] = A1 * invdet;
            Sinv[0][2] = A2 * invdet;
            Sinv[1][1] = (m00 * m22 - m02 * m02) * invdet;
            Sinv[1][2] = (m01 * m02 - m00 * m12) * invdet;
            Sinv[2][2] = (m00 * m11 - m01 * m01) * invdet;
            Sinv[1][0] = Sinv[0][1];
            Sinv[2][0] = Sinv[0][2];
            Sinv[2][1] = Sinv[1][2];

            // K = c1 @ Sinv
            float K[3][3];
#pragma unroll
            for (int a = 0; a < 3; ++a) {
#pragma unroll
                for (int b = 0; b < 3; ++b) {
                    float v = 0.f;
#pragma unroll
                    for (int k = 0; k < 3; ++k)
                        v = fmaf(c1[a][k], Sinv[k][b], v);
                    K[a][b] = v;
                }
            }

            // loc_new = loc1 + K @ (loc2 - loc1)
            const float d0 = l2[0] - l1[0], d1 = l2[1] - l1[1], d2 = l2[2] - l1[2];
#pragma unroll
            for (int a = 0; a < 3; ++a) {
                float v = fmaf(K[a][0], d0, fmaf(K[a][1], d1, K[a][2] * d2));
                sOut[tid * 3 + a] = l1[a] + v;
            }

            // cov_new = c1 + K @ c1
#pragma unroll
            for (int a = 0; a < 3; ++a) {
#pragma unroll
                for (int b = 0; b < 3; ++b) {
                    float v = 0.f;
#pragma unroll
                    for (int k = 0; k < 3; ++k)
                        v = fmaf(K[a][k], c1[k][b], v);
                    sOut[384 + tid * 9 + a * 3 + b] = c1[a][b] + v;
                }
            }
        }
        __syncthreads();   // barrier 2: sOut ready; all sIn reads done

        // ---- cooperative non-temporal store of tile t ----
        // nt: don't let our 96 MB of output evict L3-resident inputs.
#pragma unroll
        for (int w = 0; w < 3; ++w) {
            int j = tid + TILE * w;          // j in [0, 384)
            f4 v = ((const f4*)sOut)[j];
            if (j < 96) __builtin_nontemporal_store(v, (f4*)out_loc + t * 96 + j);
            else        __builtin_nontemporal_store(v, (f4*)out_cov + t * 288 + (j - 96));
        }
        // no barrier needed here: next iteration writes sIn (disjoint from sOut);
        // barrier 1 orders this store-phase's sOut reads vs next compute's writes.
    }
}

// Generic scalar tail (never launched at n = 2,000,000; kept for robustness).
__global__ void gaussian_merge_tail(
    const float* __restrict__ loc1, const float* __restrict__ scale1,
    const float* __restrict__ rot1, const float* __restrict__ loc2,
    const float* __restrict__ scale2, const float* __restrict__ rot2,
    float* __restrict__ out_loc, float* __restrict__ out_cov,
    int start, int n)
{
    int i = start + blockIdx.x * blockDim.x + threadIdx.x;
    if (i >= n) return;
    const long ib3 = (long)i * 3, ib9 = (long)i * 9;
    float R1[9], R2[9], l1[3], l2[3], s1[3], s2[3];
    for (int k = 0; k < 9; ++k) { R1[k] = rot1[ib9 + k]; R2[k] = rot2[ib9 + k]; }
    for (int k = 0; k < 3; ++k) {
        l1[k] = loc1[ib3 + k]; l2[k] = loc2[ib3 + k];
        s1[k] = scale1[ib3 + k]; s2[k] = scale2[ib3 + k];
    }
    float c1[3][3], S[3][3];
    for (int a = 0; a < 3; ++a)
        for (int b = 0; b < 3; ++b) {
            float v1 = 0.f, v2 = 0.f;
            for (int k = 0; k < 3; ++k) {
                v1 = fmaf(R1[a * 3 + k] * s1[k], R1[b * 3 + k], v1);
                v2 = fmaf(R2[a * 3 + k] * s2[k], R2[b * 3 + k], v2);
            }
            c1[a][b] = v1; S[a][b] = v1 + v2 + (a == b ? GM_EPS : 0.f);
        }
    const float m00 = S[0][0], m01 = S[0][1], m02 = S[0][2];
    const float m11 = S[1][1], m12 = S[1][2], m22 = S[2][2];
    const float A0 = m11 * m22 - m12 * m12;
    const float A1 = m02 * m12 - m01 * m22;
    const float A2 = m01 * m12 - m02 * m11;
    const float invdet = 1.0f / (m00 * A0 + m01 * A1 + m02 * A2);
    float Si[3][3];
    Si[0][0] = A0 * invdet; Si[0][1] = A1 * invdet; Si[0][2] = A2 * invdet;
    Si[1][1] = (m00 * m22 - m02 * m02) * invdet;
    Si[1][2] = (m01 * m02 - m00 * m12) * invdet;
    Si[2][2] = (m00 * m11 - m01 * m01) * invdet;
    Si[1][0] = Si[0][1]; Si[2][0] = Si[0][2]; Si[2][1] = Si[1][2];
    float K[3][3];
    for (int a = 0; a < 3; ++a)
        for (int b = 0; b < 3; ++b) {
            float v = 0.f;
            for (int k = 0; k < 3; ++k) v = fmaf(c1[a][k], Si[k][b], v);
            K[a][b] = v;
        }
    const float d0 = l2[0] - l1[0], d1 = l2[1] - l1[1], d2 = l2[2] - l1[2];
    for (int a = 0; a < 3; ++a)
        out_loc[ib3 + a] = l1[a] + fmaf(K[a][0], d0, fmaf(K[a][1], d1, K[a][2] * d2));
    for (int a = 0; a < 3; ++a)
        for (int b = 0; b < 3; ++b) {
            float v = 0.f;
            for (int k = 0; k < 3; ++k) v = fmaf(K[a][k], c1[k][b], v);
            out_cov[ib9 + a * 3 + b] = c1[a][b] + v;
        }
}

extern "C" void kernel_launch(void* const* d_in, const int* in_sizes, int n_in,
                              void* d_out, int out_size, void* d_ws, size_t ws_size,
                              hipStream_t stream) {
    const float* loc1   = (const float*)d_in[0];
    const float* scale1 = (const float*)d_in[1];
    const float* rot1   = (const float*)d_in[2];
    const float* loc2   = (const float*)d_in[3];
    const float* scale2 = (const float*)d_in[4];
    const float* rot2   = (const float*)d_in[5];
    // d_in[6], d_in[7] = cov1/cov2 placeholders: reference recomputes them.

    const int n = in_sizes[0] / 3;  // loc1 is [n,3]

    float* out     = (float*)d_out;
    float* out_loc = out;                  // [n,3]
    float* out_cov = out + (size_t)n * 3;  // [n,3,3]

    const int nTiles = n / TILE;
    const int rem    = n - nTiles * TILE;

    if (nTiles > 0) {
        const int grid = (nTiles < GRID) ? nTiles : GRID;
        gaussian_merge_kernel<<<grid, TILE, 0, stream>>>(
            loc1, scale1, rot1, loc2, scale2, rot2, out_loc, out_cov, nTiles);
    }
    if (rem > 0) {  // never at n = 2,000,000; structurally fixed per problem
        gaussian_merge_tail<<<(rem + 63) / 64, 64, 0, stream>>>(
            loc1, scale1, rot1, loc2, scale2, rot2, out_loc, out_cov,
            nTiles * TILE, n);
    }
}